// Round 14
// baseline (193.272 us; speedup 1.0000x reference)
//
#include <hip/hip_runtime.h>
#include <hip/hip_bf16.h>

#define N_NODES 4096
#define DIMC    256   // H*D, also K of both layer GEMMs
#define NHEADS  4
#define LOG2E   1.44269504f

typedef __attribute__((ext_vector_type(8))) short  short8;
typedef __attribute__((ext_vector_type(4))) short  short4v;
typedef __attribute__((ext_vector_type(4))) float  float4v;

union S8U { short8 v; unsigned int u[4]; };

#if __has_builtin(__builtin_amdgcn_exp2f)
#define EXP2(x) __builtin_amdgcn_exp2f(x)
#else
#define EXP2(x) exp2f(x)
#endif

__device__ inline unsigned short bf16_bits(__hip_bfloat16 b) {
  union { __hip_bfloat16 b; unsigned short u; } cv; cv.b = b; return cv.u;
}

// Fragment-packed layout (operand of mfma_f32_16x16x32_bf16):
//   element (row r, k) lives at u16 index
//   ((r>>4)*8 + (k>>5))*512 + (((k>>3)&3)*16 + (r&15))*8 + (k&7)
// so a wave (lane = quad*16+col) loads one 16-row x 32-k fragment as a
// single contiguous 1-KB dwordx4 stream at frag_base + lane*8.
__device__ inline size_t packidx(int r, int k) {
  return ((size_t)(r >> 4) * 8 + (k >> 5)) * 512
       + (((k >> 3) & 3) * 16 + (r & 15)) * 8 + (k & 7);
}

// ------------- fused preprocessing: one dispatch, 4 phases ---------------
//  blocks [0, 65536)          : adjacency -> bitmask (massively parallel;
//                               round-11's serial tail-fusion cost +35 us)
//  blocks [65536, 66048)      : x fp32 -> A-fragment-packed split bf16
//  blocks [66048, 66112)      : W1/W2 -> B-fragment-packed split bf16
//  blocks [66112, 66176)      : zero the f1/f2 accumulators (256 KB)
__global__ __launch_bounds__(256) void prep_kernel(
    const int* __restrict__ adj, unsigned long long* __restrict__ bits,
    const float* __restrict__ x,
    unsigned short* __restrict__ xh, unsigned short* __restrict__ xl,
    const float* __restrict__ W1, const float* __restrict__ W2,
    unsigned short* __restrict__ w1h, unsigned short* __restrict__ w1l,
    unsigned short* __restrict__ w2h, unsigned short* __restrict__ w2l,
    float* __restrict__ f12zero)
{
  int b = blockIdx.x, t = threadIdx.x;
  if (b < 65536) {                      // ---- pack_adj
    int wid  = b * 4 + (t >> 6);
    int lane = t & 63;
    int row  = wid >> 6;
    int w64  = wid & 63;
    int v = adj[(size_t)row * N_NODES + w64 * 64 + lane];
    unsigned long long m = __ballot(v > 0);
    if (lane == 0) bits[row * 64 + w64] = m;
  } else if (b < 66048) {               // ---- split_pack (x)
    int g = (b - 65536) * 256 + t;      // 131072 threads
    int n = g >> 5, kb = (g & 31) * 8;
    const float* ip = x + (size_t)n * DIMC + kb;
    float4v v0 = *reinterpret_cast<const float4v*>(ip);
    float4v v1 = *reinterpret_cast<const float4v*>(ip + 4);
    short8 oh, ol;
#pragma unroll
    for (int i = 0; i < 8; ++i) {
      float f = (i < 4) ? v0[i] : v1[i - 4];
      __hip_bfloat16 hb = __float2bfloat16(f);
      oh[i] = (short)bf16_bits(hb);
      ol[i] = (short)bf16_bits(__float2bfloat16(f - __bfloat162float(hb)));
    }
    size_t idx = packidx(n, kb);
    *reinterpret_cast<short8*>(xh + idx) = oh;
    *reinterpret_cast<short8*>(xl + idx) = ol;
  } else if (b < 66112) {               // ---- wpack (W1 / W2)
    int bid = b - 66048;
    const float* W = (bid >> 5) ? W2 : W1;
    unsigned short* hi = (bid >> 5) ? w2h : w1h;
    unsigned short* lo = (bid >> 5) ? w2l : w1l;
    int g = (bid & 31) * 256 + t;       // 8192 threads per layer
    int c = g >> 5, kb = (g & 31) * 8;
    int h = c >> 6, d = c & 63;
    const float* wp = W + (size_t)h * DIMC * 64 + (size_t)kb * 64 + d;
    short8 oh, ol;
#pragma unroll
    for (int i = 0; i < 8; ++i) {
      float f = wp[i * 64];
      __hip_bfloat16 hb = __float2bfloat16(f);
      oh[i] = (short)bf16_bits(hb);
      ol[i] = (short)bf16_bits(__float2bfloat16(f - __bfloat162float(hb)));
    }
    size_t idx = packidx(c, kb);
    *reinterpret_cast<short8*>(hi + idx) = oh;
    *reinterpret_cast<short8*>(lo + idx) = ol;
  } else {                              // ---- zero f1/f2 (256 KB)
    int z = b - 66112;                  // 0..63
    reinterpret_cast<float4v*>(f12zero)[(size_t)z * 256 + t] = {0, 0, 0, 0};
  }
}

// ------- h GEMM (fragment-packed split-bf16) + f-vec + Bpack epilogue ----
// All four operand streams are contiguous 1-KB wave-loads per K-step.
// 3 independent MFMA accumulators (summed at end): 3x MFMA ILP.
// Epilogue 1: f1/f2 partials via 16-lane shfl reduce + atomicAdd.
// Epilogue 2: Bpack (V in attn B-fragment order) via LDS transpose.
// grid (128,8), block 256. blockIdx.x == jt, head = blockIdx.y>>1.
__global__ __launch_bounds__(256) void gemm_kernel(
    const unsigned short* __restrict__ Ah, const unsigned short* __restrict__ Al,
    const unsigned short* __restrict__ Bh, const unsigned short* __restrict__ Bl,
    const float* __restrict__ avec,
    float* __restrict__ f1L, float* __restrict__ f2L,
    unsigned short* __restrict__ Bpack)
{
  __shared__ float tl[32][33];
  int t = threadIdx.x;
  int wv = t >> 6, lane = t & 63, quad = lane >> 4, col = lane & 15;
  int bc = blockIdx.y * 32;
  int rt = blockIdx.x * 2 + (wv >> 1);   // 16-row tile index
  int ct = blockIdx.y * 2 + (wv & 1);    // 16-col tile index
  int r0 = blockIdx.x * 32 + (wv >> 1) * 16;
  int c0 = bc + (wv & 1) * 16;
  float4v aHH = {0,0,0,0}, aHL = {0,0,0,0}, aLH = {0,0,0,0};
  const unsigned short* ahp = Ah + (size_t)rt * 4096 + lane * 8;
  const unsigned short* alp = Al + (size_t)rt * 4096 + lane * 8;
  const unsigned short* bhp = Bh + (size_t)ct * 4096 + lane * 8;
  const unsigned short* blp = Bl + (size_t)ct * 4096 + lane * 8;
#pragma unroll
  for (int ks = 0; ks < 8; ++ks) {
    short8 ah = *reinterpret_cast<const short8*>(ahp + ks * 512);
    short8 al = *reinterpret_cast<const short8*>(alp + ks * 512);
    short8 bh = *reinterpret_cast<const short8*>(bhp + ks * 512);
    short8 bl = *reinterpret_cast<const short8*>(blp + ks * 512);
    aHH = __builtin_amdgcn_mfma_f32_16x16x32_bf16(ah, bh, aHH, 0, 0, 0);
    aHL = __builtin_amdgcn_mfma_f32_16x16x32_bf16(ah, bl, aHL, 0, 0, 0);
    aLH = __builtin_amdgcn_mfma_f32_16x16x32_bf16(al, bh, aLH, 0, 0, 0);
  }
  float4v acc = aHH + aHL + aLH;

  // ---- f1/f2 partial reduction (this block's 16-col slice of head hh)
  int hh = blockIdx.y >> 1;
  int d0 = (c0 + col) & 63;
  float av1 = avec[hh * 128 + d0];
  float av2 = avec[hh * 128 + 64 + d0];
#pragma unroll
  for (int r = 0; r < 4; ++r) {
    float v1 = acc[r] * av1;
    float v2 = acc[r] * av2;
#pragma unroll
    for (int o = 8; o >= 1; o >>= 1) {
      v1 += __shfl_xor(v1, o);
      v2 += __shfl_xor(v2, o);
    }
    if ((lane & 15) == 0) {
      int n = r0 + quad * 4 + r;
      atomicAdd(f1L + hh * N_NODES + n, v1 * LOG2E);
      atomicAdd(f2L + hh * N_NODES + n, v2 * LOG2E);
    }
  }

  // ---- Bpack epilogue (via LDS transpose of the 32x32 tile)
  int lr = (wv >> 1) * 16 + quad * 4, lc = (wv & 1) * 16 + col;
#pragma unroll
  for (int r = 0; r < 4; ++r) tl[lr + r][lc] = acc[r];
  __syncthreads();
  int tr = t >> 3, tc = (t & 7) * 4;   // tr: local c, tc: local j (4-wide)
  short4v oh;
#pragma unroll
  for (int k = 0; k < 4; ++k)
    oh[k] = (short)bf16_bits(__float2bfloat16(tl[tc + k][tr]));
  int c = bc + tr;
  int h = c >> 6, d = c & 63, db = d >> 4, colp = d & 15;
  int quadp = tc >> 3, jj = tc & 7;    // jj in {0,4}
  size_t fragu = (((size_t)(h * 128 + blockIdx.x) * 4 + db) * 64
                  + quadp * 16 + colp) * 8 + jj;
  *reinterpret_cast<short4v*>(Bpack + fragu) = oh;
}

// ------ fused masked-softmax attention, fragment-packed + prefetch -------
// grid (128, 4), block 512 = 8 waves, wave wv owns j in [wv*512,(wv+1)*512)
// for the SAME 32 i-rows (2 A-fragments per B-fragment, 10 MFMA / 4-KB).
// NEW vs round 12: explicit 1-step register prefetch of {b0..b3, fa, fb} --
// step s+1's loads issue before step s's ~400-cy weight-VALU+MFMA block,
// hiding the L2 round-trip that left the loop ~80% stalled (issue floor
// ~4.5 us/CU vs ~26 us measured). Step-0 loads issue BEFORE the f2-max
// LDS tree so they hide under its 9 barriers. Same values, same order --
// bit-exact vs round 12.
__global__ __launch_bounds__(512, 4) void attn_kernel(
    const unsigned short* __restrict__ Bpack,
    const float* __restrict__ f1L, const float* __restrict__ f2L,
    const unsigned long long* __restrict__ bits64, // [4096][64]
    float* __restrict__ outf, unsigned short* __restrict__ outhi,
    unsigned short* __restrict__ outlo)
{
  __shared__ __align__(16) float part[8][32][68];  // 69.6 KB (aliased below)
  unsigned long long* lds_bits =
      reinterpret_cast<unsigned long long*>(&part[0][0][0]); // 16 KB: [tile][row]
  float* red = reinterpret_cast<float*>(&part[2][0][0]);     // 2 KB @ 17408
  int t = threadIdx.x;
  int wv = t >> 6, lane = t & 63, quad = lane >> 4, col = lane & 15;
  int it = blockIdx.x, h = blockIdx.y;
  int i0 = it * 32;
  int irow0 = i0 + col;              // rows for A-fragment 0
  int irow1 = i0 + 16 + col;         // rows for A-fragment 1

  const float* f2h = f2L + h * N_NODES;
  // wave's fragment stream: 16 steps x 4 db x 512 u16, contiguous
  const unsigned short* bp =
      Bpack + ((size_t)(h * 128 + wv * 16)) * 4 * 512 + lane * 8;
  int jbase = wv * 512;

  // ---- pipeline prologue: step-0 loads in flight during the LDS phases
  short8 b0n = *reinterpret_cast<const short8*>(bp);
  short8 b1n = *reinterpret_cast<const short8*>(bp + 512);
  short8 b2n = *reinterpret_cast<const short8*>(bp + 1024);
  short8 b3n = *reinterpret_cast<const short8*>(bp + 1536);
  float4v fa_n = *reinterpret_cast<const float4v*>(f2h + jbase + quad * 8);
  float4v fb_n = *reinterpret_cast<const float4v*>(f2h + jbase + quad * 8 + 4);

  // ---- mask preload: 32 rows x 64 tiles, coalesced read, [tile][row] LDS
  {
    int rr = t >> 4, tt = (t & 15) * 4;
    const unsigned long long* gsrc = bits64 + (size_t)(i0 + rr) * 64 + tt;
    unsigned long long m0 = gsrc[0], m1 = gsrc[1], m2 = gsrc[2], m3 = gsrc[3];
    lds_bits[(tt + 0) * 32 + rr] = m0;
    lds_bits[(tt + 1) * 32 + rr] = m1;
    lds_bits[(tt + 2) * 32 + rr] = m2;
    lds_bits[(tt + 3) * 32 + rr] = m3;
  }

  // ---- per-head f2 max over all 4096 nodes (LDS tree)
  {
    float4v ma = *reinterpret_cast<const float4v*>(f2h + t * 8);
    float4v mb = *reinterpret_cast<const float4v*>(f2h + t * 8 + 4);
    red[t] = fmaxf(fmaxf(fmaxf(ma[0], ma[1]), fmaxf(ma[2], ma[3])),
                   fmaxf(fmaxf(mb[0], mb[1]), fmaxf(mb[2], mb[3])));
  }
  __syncthreads();
#pragma unroll
  for (int s2 = 256; s2 >= 1; s2 >>= 1) {
    if (t < s2) red[t] = fmaxf(red[t], red[t + s2]);
    __syncthreads();
  }
  float f2m = red[0];

  float f1i0 = f1L[h * N_NODES + irow0];
  float f1i1 = f1L[h * N_NODES + irow1];
  float s00 = f1i0 + f2m;
  float m0 = fmaxf(s00, 0.2f * s00); // lrelu monotone -> valid upper-bound shift
  float f1m0 = f1i0 - m0;
  float cm0 = -0.8f * m0;
  float s01 = f1i1 + f2m;
  float m1 = fmaxf(s01, 0.2f * s01);
  float f1m1 = f1i1 - m1;
  float cm1 = -0.8f * m1;

  float4v acc0[4] = {{0,0,0,0},{0,0,0,0},{0,0,0,0},{0,0,0,0}};
  float4v acc1[4] = {{0,0,0,0},{0,0,0,0},{0,0,0,0},{0,0,0,0}};
  float4v accl0 = {0, 0, 0, 0}, accl1 = {0, 0, 0, 0};
  S8U ones;
  ones.u[0] = ones.u[1] = ones.u[2] = ones.u[3] = 0x3F803F80u; // bf16 1.0 x2

  for (int s = 0; s < 16; ++s) {     // 16 x 32-j steps, no barriers
    // consume pipeline registers (loaded one step ahead)
    short8 b0 = b0n, b1 = b1n, b2 = b2n, b3 = b3n;
    float4v fa = fa_n, fb = fb_n;
    if (s < 15) {                    // issue next step's loads NOW
      const unsigned short* bs = bp + (size_t)(s + 1) * 2048;
      b0n = *reinterpret_cast<const short8*>(bs);
      b1n = *reinterpret_cast<const short8*>(bs + 512);
      b2n = *reinterpret_cast<const short8*>(bs + 1024);
      b3n = *reinterpret_cast<const short8*>(bs + 1536);
      const float* fp = f2h + jbase + (s + 1) * 32 + quad * 8;
      fa_n = *reinterpret_cast<const float4v*>(fp);
      fb_n = *reinterpret_cast<const float4v*>(fp + 4);
    }
    int j0 = jbase + s * 32;
    int tg = j0 >> 6;                // global mask tile = wv*8 + (s>>1)
    unsigned long long wq0 = lds_bits[tg * 32 + col];
    unsigned long long wq1 = lds_bits[tg * 32 + col + 16];
    int sh = (j0 & 32) | (quad * 8);
    unsigned wb0 = (unsigned)(wq0 >> sh);
    unsigned wb1 = (unsigned)(wq1 >> sh);
    float w0[8], w1[8];
#pragma unroll
    for (int jj = 0; jj < 8; ++jj) {
      float fv = (jj < 4) ? fa[jj] : fb[jj - 4];
      float sp0 = f1m0 + fv;
      float tb0 = __builtin_fmaf(0.2f, sp0, cm0);
      float e0 = EXP2(fmaxf(sp0, tb0));
      w0[jj] = (wb0 & (1u << jj)) ? e0 : 0.0f;
      float sp1 = f1m1 + fv;
      float tb1 = __builtin_fmaf(0.2f, sp1, cm1);
      float e1 = EXP2(fmaxf(sp1, tb1));
      w1[jj] = (wb1 & (1u << jj)) ? e1 : 0.0f;
    }
    S8U afr0, afr1;
#pragma unroll
    for (int k2 = 0; k2 < 4; ++k2) { // truncate-pack two fp32 -> bf16x2
      afr0.u[k2] = __builtin_amdgcn_perm(__float_as_uint(w0[2 * k2 + 1]),
                                         __float_as_uint(w0[2 * k2]),
                                         0x07060302u);
      afr1.u[k2] = __builtin_amdgcn_perm(__float_as_uint(w1[2 * k2 + 1]),
                                         __float_as_uint(w1[2 * k2]),
                                         0x07060302u);
    }
    acc0[0] = __builtin_amdgcn_mfma_f32_16x16x32_bf16(afr0.v, b0, acc0[0], 0, 0, 0);
    acc0[1] = __builtin_amdgcn_mfma_f32_16x16x32_bf16(afr0.v, b1, acc0[1], 0, 0, 0);
    acc0[2] = __builtin_amdgcn_mfma_f32_16x16x32_bf16(afr0.v, b2, acc0[2], 0, 0, 0);
    acc0[3] = __builtin_amdgcn_mfma_f32_16x16x32_bf16(afr0.v, b3, acc0[3], 0, 0, 0);
    accl0   = __builtin_amdgcn_mfma_f32_16x16x32_bf16(afr0.v, ones.v, accl0, 0, 0, 0);
    acc1[0] = __builtin_amdgcn_mfma_f32_16x16x32_bf16(afr1.v, b0, acc1[0], 0, 0, 0);
    acc1[1] = __builtin_amdgcn_mfma_f32_16x16x32_bf16(afr1.v, b1, acc1[1], 0, 0, 0);
    acc1[2] = __builtin_amdgcn_mfma_f32_16x16x32_bf16(afr1.v, b2, acc1[2], 0, 0, 0);
    acc1[3] = __builtin_amdgcn_mfma_f32_16x16x32_bf16(afr1.v, b3, acc1[3], 0, 0, 0);
    accl1   = __builtin_amdgcn_mfma_f32_16x16x32_bf16(afr1.v, ones.v, accl1, 0, 0, 0);
  }

  __syncthreads();   // all mask/red reads complete before aliased part writes

  // C/D layout: col=lane&15 (d sub-col), row=quad*4+reg (i). Park partials.
#pragma unroll
  for (int db = 0; db < 4; ++db)
#pragma unroll
    for (int r = 0; r < 4; ++r) {
      part[wv][quad * 4 + r][db * 16 + col] = acc0[db][r];
      part[wv][16 + quad * 4 + r][db * 16 + col] = acc1[db][r];
    }
  if (col == 0) {
#pragma unroll
    for (int r = 0; r < 4; ++r) {
      part[wv][quad * 4 + r][64] = accl0[r];
      part[wv][16 + quad * 4 + r][64] = accl1[r];
    }
  }
  __syncthreads();

  // 512 threads: t -> (row = t>>4 in 0..31, 4 d at (t&15)*4). Sum 8 partials.
  int row = t >> 4, dd = (t & 15) * 4;
  float4v s = {0, 0, 0, 0};
  float l = 0.f;
#pragma unroll
  for (int w2 = 0; w2 < 8; ++w2) {
    float4v pv = *reinterpret_cast<const float4v*>(&part[w2][row][dd]);
    s += pv;
    l += part[w2][row][64];
  }
  float rl = 1.0f / l;
  float o[4];
#pragma unroll
  for (int r = 0; r < 4; ++r) {
    float v = s[r] * rl;
    o[r] = v > 0.f ? v : EXP2(v * LOG2E) - 1.0f;
  }
  int n2 = i0 + row;
  if (outf) {
    size_t oo = (size_t)n2 * DIMC + h * 64 + dd;
    *reinterpret_cast<float4v*>(outf + oo) = {o[0], o[1], o[2], o[3]};
  } else {
    int cg = h * 64 + dd;            // global col (multiple of 4)
    size_t pidx = packidx(n2, cg);   // A-fragment-packed for layer-2 GEMM
    short4v ohv, olv;
#pragma unroll
    for (int r = 0; r < 4; ++r) {
      __hip_bfloat16 hb = __float2bfloat16(o[r]);
      ohv[r] = (short)bf16_bits(hb);
      olv[r] = (short)bf16_bits(__float2bfloat16(o[r] - __bfloat162float(hb)));
    }
    *reinterpret_cast<short4v*>(outhi + pidx) = ohv;
    *reinterpret_cast<short4v*>(outlo + pidx) = olv;
  }
}

extern "C" void kernel_launch(void* const* d_in, const int* in_sizes, int n_in,
                              void* d_out, int out_size, void* d_ws, size_t ws_size,
                              hipStream_t stream)
{
  // inputs: t, x, adj, W1, a1, W2, a2  (fp32 except adj int32)
  const float* x   = (const float*)d_in[1];
  const int*   adj = (const int*)d_in[2];
  const float* W1  = (const float*)d_in[3];
  const float* a1  = (const float*)d_in[4];
  const float* W2  = (const float*)d_in[5];
  const float* a2  = (const float*)d_in[6];

  char* ws = (char*)d_ws;
  size_t off = 0;
  auto alloc = [&](size_t b) { size_t o = off; off = (off + b + 255) & ~255ULL; return o; };
  size_t o_bits = alloc((size_t)N_NODES * 64 * 8);          // 2 MB bitmask
  size_t o_w1h  = alloc((size_t)DIMC * DIMC * 2);           // packed weights
  size_t o_w1l  = alloc((size_t)DIMC * DIMC * 2);
  size_t o_w2h  = alloc((size_t)DIMC * DIMC * 2);
  size_t o_w2l  = alloc((size_t)DIMC * DIMC * 2);
  size_t o_xh   = alloc((size_t)N_NODES * DIMC * 2);        // packed A operand
  size_t o_xl   = alloc((size_t)N_NODES * DIMC * 2);
  size_t o_bp   = alloc((size_t)N_NODES * DIMC * 2);        // Bpack (2 MB)
  size_t o_x2h  = alloc((size_t)N_NODES * DIMC * 2);        // packed layer-2 A
  size_t o_x2l  = alloc((size_t)N_NODES * DIMC * 2);
  size_t o_f12  = alloc((size_t)4 * NHEADS * N_NODES * 4);  // f1a,f2a,f1b,f2b

  unsigned long long* bits = (unsigned long long*)(ws + o_bits);
  unsigned short* w1h = (unsigned short*)(ws + o_w1h);
  unsigned short* w1l = (unsigned short*)(ws + o_w1l);
  unsigned short* w2h = (unsigned short*)(ws + o_w2h);
  unsigned short* w2l = (unsigned short*)(ws + o_w2l);
  unsigned short* xh  = (unsigned short*)(ws + o_xh);
  unsigned short* xl  = (unsigned short*)(ws + o_xl);
  unsigned short* bpk = (unsigned short*)(ws + o_bp);
  unsigned short* x2h = (unsigned short*)(ws + o_x2h);
  unsigned short* x2l = (unsigned short*)(ws + o_x2l);
  float* f12 = (float*)(ws + o_f12);
  float* f1a = f12;
  float* f2a = f12 + NHEADS * N_NODES;
  float* f1b = f12 + 2 * NHEADS * N_NODES;
  float* f2b = f12 + 3 * NHEADS * N_NODES;

  prep_kernel<<<66176, 256, 0, stream>>>(adj, bits, x, xh, xl, W1, W2,
                                         w1h, w1l, w2h, w2l, f12);

  auto layer = [&](const unsigned short* xih, const unsigned short* xil,
                   const unsigned short* wth, const unsigned short* wtl,
                   const float* av, float* f1p, float* f2p, float* outf,
                   unsigned short* oh, unsigned short* ol) {
    gemm_kernel<<<dim3(128, 8), 256, 0, stream>>>(xih, xil, wth, wtl, av,
                                                  f1p, f2p, bpk);
    attn_kernel<<<dim3(128, 4), 512, 0, stream>>>(bpk, f1p, f2p, bits,
                                                  outf, oh, ol);
  };

  layer(xh,  xl,  w1h, w1l, a1, f1a, f2a, nullptr,       x2h, x2l);
  layer(x2h, x2l, w2h, w2l, a2, f1b, f2b, (float*)d_out, nullptr, nullptr);
}

// Round 15
// 192.984 us; speedup vs baseline: 1.0015x; 1.0015x over previous
//
#include <hip/hip_runtime.h>
#include <hip/hip_bf16.h>

#define N_NODES 4096
#define DIMC    256   // H*D, also K of both layer GEMMs
#define NHEADS  4
#define LOG2E   1.44269504f

typedef __attribute__((ext_vector_type(8))) short  short8;
typedef __attribute__((ext_vector_type(4))) short  short4v;
typedef __attribute__((ext_vector_type(4))) float  float4v;

union S8U { short8 v; unsigned int u[4]; };

#if __has_builtin(__builtin_amdgcn_exp2f)
#define EXP2(x) __builtin_amdgcn_exp2f(x)
#else
#define EXP2(x) exp2f(x)
#endif

__device__ inline unsigned short bf16_bits(__hip_bfloat16 b) {
  union { __hip_bfloat16 b; unsigned short u; } cv; cv.b = b; return cv.u;
}

// Fragment-packed layout (operand of mfma_f32_16x16x32_bf16):
//   element (row r, k) lives at u16 index
//   ((r>>4)*8 + (k>>5))*512 + (((k>>3)&3)*16 + (r&15))*8 + (k&7)
// so a wave (lane = quad*16+col) loads one 16-row x 32-k fragment as a
// single contiguous 1-KB dwordx4 stream at frag_base + lane*8.
__device__ inline size_t packidx(int r, int k) {
  return ((size_t)(r >> 4) * 8 + (k >> 5)) * 512
       + (((k >> 3) & 3) * 16 + (r & 15)) * 8 + (k & 7);
}

// ------------- fused preprocessing: one dispatch, 4 phases ---------------
//  blocks [0, 65536)          : adjacency -> bitmask (massively parallel;
//                               round-11's serial tail-fusion cost +35 us)
//  blocks [65536, 66048)      : x fp32 -> A-fragment-packed split bf16
//  blocks [66048, 66112)      : W1/W2 -> B-fragment-packed split bf16
//  blocks [66112, 66176)      : zero the f1/f2 accumulators (256 KB)
__global__ __launch_bounds__(256) void prep_kernel(
    const int* __restrict__ adj, unsigned long long* __restrict__ bits,
    const float* __restrict__ x,
    unsigned short* __restrict__ xh, unsigned short* __restrict__ xl,
    const float* __restrict__ W1, const float* __restrict__ W2,
    unsigned short* __restrict__ w1h, unsigned short* __restrict__ w1l,
    unsigned short* __restrict__ w2h, unsigned short* __restrict__ w2l,
    float* __restrict__ f12zero)
{
  int b = blockIdx.x, t = threadIdx.x;
  if (b < 65536) {                      // ---- pack_adj
    int wid  = b * 4 + (t >> 6);
    int lane = t & 63;
    int row  = wid >> 6;
    int w64  = wid & 63;
    int v = adj[(size_t)row * N_NODES + w64 * 64 + lane];
    unsigned long long m = __ballot(v > 0);
    if (lane == 0) bits[row * 64 + w64] = m;
  } else if (b < 66048) {               // ---- split_pack (x)
    int g = (b - 65536) * 256 + t;      // 131072 threads
    int n = g >> 5, kb = (g & 31) * 8;
    const float* ip = x + (size_t)n * DIMC + kb;
    float4v v0 = *reinterpret_cast<const float4v*>(ip);
    float4v v1 = *reinterpret_cast<const float4v*>(ip + 4);
    short8 oh, ol;
#pragma unroll
    for (int i = 0; i < 8; ++i) {
      float f = (i < 4) ? v0[i] : v1[i - 4];
      __hip_bfloat16 hb = __float2bfloat16(f);
      oh[i] = (short)bf16_bits(hb);
      ol[i] = (short)bf16_bits(__float2bfloat16(f - __bfloat162float(hb)));
    }
    size_t idx = packidx(n, kb);
    *reinterpret_cast<short8*>(xh + idx) = oh;
    *reinterpret_cast<short8*>(xl + idx) = ol;
  } else if (b < 66112) {               // ---- wpack (W1 / W2)
    int bid = b - 66048;
    const float* W = (bid >> 5) ? W2 : W1;
    unsigned short* hi = (bid >> 5) ? w2h : w1h;
    unsigned short* lo = (bid >> 5) ? w2l : w1l;
    int g = (bid & 31) * 256 + t;       // 8192 threads per layer
    int c = g >> 5, kb = (g & 31) * 8;
    int h = c >> 6, d = c & 63;
    const float* wp = W + (size_t)h * DIMC * 64 + (size_t)kb * 64 + d;
    short8 oh, ol;
#pragma unroll
    for (int i = 0; i < 8; ++i) {
      float f = wp[i * 64];
      __hip_bfloat16 hb = __float2bfloat16(f);
      oh[i] = (short)bf16_bits(hb);
      ol[i] = (short)bf16_bits(__float2bfloat16(f - __bfloat162float(hb)));
    }
    size_t idx = packidx(c, kb);
    *reinterpret_cast<short8*>(hi + idx) = oh;
    *reinterpret_cast<short8*>(lo + idx) = ol;
  } else {                              // ---- zero f1/f2 (256 KB)
    int z = b - 66112;                  // 0..63
    reinterpret_cast<float4v*>(f12zero)[(size_t)z * 256 + t] = {0, 0, 0, 0};
  }
}

// ------- h GEMM (fragment-packed split-bf16) + f-vec + Bpack epilogue ----
// All four operand streams are contiguous 1-KB wave-loads per K-step.
// 3 independent MFMA accumulators (summed at end): 3x MFMA ILP.
// Epilogue 1: f1/f2 partials via 16-lane shfl reduce + atomicAdd.
// Epilogue 2: Bpack (V in attn B-fragment order) via LDS transpose.
// grid (128,8), block 256. blockIdx.x == jt, head = blockIdx.y>>1.
__global__ __launch_bounds__(256) void gemm_kernel(
    const unsigned short* __restrict__ Ah, const unsigned short* __restrict__ Al,
    const unsigned short* __restrict__ Bh, const unsigned short* __restrict__ Bl,
    const float* __restrict__ avec,
    float* __restrict__ f1L, float* __restrict__ f2L,
    unsigned short* __restrict__ Bpack)
{
  __shared__ float tl[32][33];
  int t = threadIdx.x;
  int wv = t >> 6, lane = t & 63, quad = lane >> 4, col = lane & 15;
  int bc = blockIdx.y * 32;
  int rt = blockIdx.x * 2 + (wv >> 1);   // 16-row tile index
  int ct = blockIdx.y * 2 + (wv & 1);    // 16-col tile index
  int r0 = blockIdx.x * 32 + (wv >> 1) * 16;
  int c0 = bc + (wv & 1) * 16;
  float4v aHH = {0,0,0,0}, aHL = {0,0,0,0}, aLH = {0,0,0,0};
  const unsigned short* ahp = Ah + (size_t)rt * 4096 + lane * 8;
  const unsigned short* alp = Al + (size_t)rt * 4096 + lane * 8;
  const unsigned short* bhp = Bh + (size_t)ct * 4096 + lane * 8;
  const unsigned short* blp = Bl + (size_t)ct * 4096 + lane * 8;
#pragma unroll
  for (int ks = 0; ks < 8; ++ks) {
    short8 ah = *reinterpret_cast<const short8*>(ahp + ks * 512);
    short8 al = *reinterpret_cast<const short8*>(alp + ks * 512);
    short8 bh = *reinterpret_cast<const short8*>(bhp + ks * 512);
    short8 bl = *reinterpret_cast<const short8*>(blp + ks * 512);
    aHH = __builtin_amdgcn_mfma_f32_16x16x32_bf16(ah, bh, aHH, 0, 0, 0);
    aHL = __builtin_amdgcn_mfma_f32_16x16x32_bf16(ah, bl, aHL, 0, 0, 0);
    aLH = __builtin_amdgcn_mfma_f32_16x16x32_bf16(al, bh, aLH, 0, 0, 0);
  }
  float4v acc = aHH + aHL + aLH;

  // ---- f1/f2 partial reduction (this block's 16-col slice of head hh)
  int hh = blockIdx.y >> 1;
  int d0 = (c0 + col) & 63;
  float av1 = avec[hh * 128 + d0];
  float av2 = avec[hh * 128 + 64 + d0];
#pragma unroll
  for (int r = 0; r < 4; ++r) {
    float v1 = acc[r] * av1;
    float v2 = acc[r] * av2;
#pragma unroll
    for (int o = 8; o >= 1; o >>= 1) {
      v1 += __shfl_xor(v1, o);
      v2 += __shfl_xor(v2, o);
    }
    if ((lane & 15) == 0) {
      int n = r0 + quad * 4 + r;
      atomicAdd(f1L + hh * N_NODES + n, v1 * LOG2E);
      atomicAdd(f2L + hh * N_NODES + n, v2 * LOG2E);
    }
  }

  // ---- Bpack epilogue (via LDS transpose of the 32x32 tile)
  int lr = (wv >> 1) * 16 + quad * 4, lc = (wv & 1) * 16 + col;
#pragma unroll
  for (int r = 0; r < 4; ++r) tl[lr + r][lc] = acc[r];
  __syncthreads();
  int tr = t >> 3, tc = (t & 7) * 4;   // tr: local c, tc: local j (4-wide)
  short4v oh;
#pragma unroll
  for (int k = 0; k < 4; ++k)
    oh[k] = (short)bf16_bits(__float2bfloat16(tl[tc + k][tr]));
  int c = bc + tr;
  int h = c >> 6, d = c & 63, db = d >> 4, colp = d & 15;
  int quadp = tc >> 3, jj = tc & 7;    // jj in {0,4}
  size_t fragu = (((size_t)(h * 128 + blockIdx.x) * 4 + db) * 64
                  + quadp * 16 + colp) * 8 + jj;
  *reinterpret_cast<short4v*>(Bpack + fragu) = oh;
}

// ------ fused masked-softmax attention, 64-row tiles (2x intensity) ------
// grid (64, 4) = (64-row i-tile, head). block 512 = 8 waves; wave wv owns
// j in [wv*512,(wv+1)*512) for the SAME 64 i-rows, holding FOUR A-fragment
// row-sets against each B-fragment: 20 MFMA per 4-KB B-load (2x round 13)
// and HALF the total Bpack L2/L3 traffic (256 -> 128 MB) -- the measured
// ~9 TB/s B-stream was the bottleneck (latency & TLP theories both nulled).
// 256 blocks = 1 block/CU, 2 waves/SIMD; __launch_bounds__(512,2) -> VGPR
// cap 256 (acc 64 + accl 16 + pipeline regs fit with headroom, no spill).
// Per-row j-partition unchanged (8 partials of 512) -> bit-exact numerics.
__global__ __launch_bounds__(512, 2) void attn_kernel(
    const unsigned short* __restrict__ Bpack,
    const float* __restrict__ f1L, const float* __restrict__ f2L,
    const unsigned long long* __restrict__ bits64, // [4096][64]
    float* __restrict__ outf, unsigned short* __restrict__ outhi,
    unsigned short* __restrict__ outlo)
{
  __shared__ __align__(16) float part[8][64][68];  // 139 KB (aliased below)
  unsigned long long* lds_bits =
      reinterpret_cast<unsigned long long*>(&part[0][0][0]); // 32 KB: [tile][row]
  float* red = reinterpret_cast<float*>(&part[2][0][0]);     // 2 KB @ 34816
  int t = threadIdx.x;
  int wv = t >> 6, lane = t & 63, quad = lane >> 4, col = lane & 15;
  int it = blockIdx.x, h = blockIdx.y;
  int i0 = it * 64;

  const float* f2h = f2L + h * N_NODES;
  // wave's fragment stream: 16 steps x 4 db x 512 u16, contiguous
  const unsigned short* bp =
      Bpack + ((size_t)(h * 128 + wv * 16)) * 4 * 512 + lane * 8;
  int jbase = wv * 512;

  // ---- pipeline prologue: step-0 loads in flight during the LDS phases
  short8 b0n = *reinterpret_cast<const short8*>(bp);
  short8 b1n = *reinterpret_cast<const short8*>(bp + 512);
  short8 b2n = *reinterpret_cast<const short8*>(bp + 1024);
  short8 b3n = *reinterpret_cast<const short8*>(bp + 1536);
  float4v fa_n = *reinterpret_cast<const float4v*>(f2h + jbase + quad * 8);
  float4v fb_n = *reinterpret_cast<const float4v*>(f2h + jbase + quad * 8 + 4);

  // ---- mask preload: 64 rows x 64 tiles (32 KB), coalesced, [tile][row]
  {
    int rr = t >> 3, tt = (t & 7) * 8;
    const unsigned long long* gsrc = bits64 + (size_t)(i0 + rr) * 64 + tt;
#pragma unroll
    for (int i = 0; i < 8; ++i) lds_bits[(tt + i) * 64 + rr] = gsrc[i];
  }

  // ---- per-head f2 max over all 4096 nodes (LDS tree)
  {
    float4v ma = *reinterpret_cast<const float4v*>(f2h + t * 8);
    float4v mb = *reinterpret_cast<const float4v*>(f2h + t * 8 + 4);
    red[t] = fmaxf(fmaxf(fmaxf(ma[0], ma[1]), fmaxf(ma[2], ma[3])),
                   fmaxf(fmaxf(mb[0], mb[1]), fmaxf(mb[2], mb[3])));
  }
  __syncthreads();
#pragma unroll
  for (int s2 = 256; s2 >= 1; s2 >>= 1) {
    if (t < s2) red[t] = fmaxf(red[t], red[t + s2]);
    __syncthreads();
  }
  float f2m = red[0];

  // per-rowset shift constants (rowset r covers rows i0 + r*16 + col)
  float f1m[4], cm[4];
#pragma unroll
  for (int r = 0; r < 4; ++r) {
    float f1i = f1L[h * N_NODES + i0 + r * 16 + col];
    float s0 = f1i + f2m;
    float m = fmaxf(s0, 0.2f * s0);  // lrelu monotone -> valid upper-bound shift
    f1m[r] = f1i - m;
    cm[r] = -0.8f * m;
  }

  float4v acc[4][4];                 // [rowset][db]
  float4v accl[4];
#pragma unroll
  for (int r = 0; r < 4; ++r) {
    accl[r] = (float4v){0, 0, 0, 0};
#pragma unroll
    for (int db = 0; db < 4; ++db) acc[r][db] = (float4v){0, 0, 0, 0};
  }
  S8U ones;
  ones.u[0] = ones.u[1] = ones.u[2] = ones.u[3] = 0x3F803F80u; // bf16 1.0 x2

  for (int s = 0; s < 16; ++s) {     // 16 x 32-j steps, no barriers
    short8 b0 = b0n, b1 = b1n, b2 = b2n, b3 = b3n;
    float4v fa = fa_n, fb = fb_n;
    if (s < 15) {                    // issue next step's loads now
      const unsigned short* bs = bp + (size_t)(s + 1) * 2048;
      b0n = *reinterpret_cast<const short8*>(bs);
      b1n = *reinterpret_cast<const short8*>(bs + 512);
      b2n = *reinterpret_cast<const short8*>(bs + 1024);
      b3n = *reinterpret_cast<const short8*>(bs + 1536);
      const float* fp = f2h + jbase + (s + 1) * 32 + quad * 8;
      fa_n = *reinterpret_cast<const float4v*>(fp);
      fb_n = *reinterpret_cast<const float4v*>(fp + 4);
    }
    int j0 = jbase + s * 32;
    int tg = j0 >> 6;                // global mask tile
    int sh = (j0 & 32) | (quad * 8);
#pragma unroll
    for (int r = 0; r < 4; ++r) {    // 4 row-sets share b0..b3
      unsigned wb = (unsigned)(lds_bits[tg * 64 + r * 16 + col] >> sh);
      float w[8];
#pragma unroll
      for (int jj = 0; jj < 8; ++jj) {
        float fv = (jj < 4) ? fa[jj] : fb[jj - 4];
        float sp = f1m[r] + fv;
        float tb = __builtin_fmaf(0.2f, sp, cm[r]);
        float e = EXP2(fmaxf(sp, tb));
        w[jj] = (wb & (1u << jj)) ? e : 0.0f;
      }
      S8U afr;
#pragma unroll
      for (int k2 = 0; k2 < 4; ++k2) // truncate-pack two fp32 -> bf16x2
        afr.u[k2] = __builtin_amdgcn_perm(__float_as_uint(w[2 * k2 + 1]),
                                          __float_as_uint(w[2 * k2]),
                                          0x07060302u);
      acc[r][0] = __builtin_amdgcn_mfma_f32_16x16x32_bf16(afr.v, b0, acc[r][0], 0, 0, 0);
      acc[r][1] = __builtin_amdgcn_mfma_f32_16x16x32_bf16(afr.v, b1, acc[r][1], 0, 0, 0);
      acc[r][2] = __builtin_amdgcn_mfma_f32_16x16x32_bf16(afr.v, b2, acc[r][2], 0, 0, 0);
      acc[r][3] = __builtin_amdgcn_mfma_f32_16x16x32_bf16(afr.v, b3, acc[r][3], 0, 0, 0);
      accl[r]   = __builtin_amdgcn_mfma_f32_16x16x32_bf16(afr.v, ones.v, accl[r], 0, 0, 0);
    }
  }

  __syncthreads();   // all mask/red reads complete before aliased part writes

  // C/D layout: col=lane&15 (d sub-col), row=quad*4+reg (i). Park partials.
#pragma unroll
  for (int r = 0; r < 4; ++r) {
#pragma unroll
    for (int db = 0; db < 4; ++db)
#pragma unroll
      for (int rg = 0; rg < 4; ++rg)
        part[wv][r * 16 + quad * 4 + rg][db * 16 + col] = acc[r][db][rg];
    if (col == 0) {
#pragma unroll
      for (int rg = 0; rg < 4; ++rg)
        part[wv][r * 16 + quad * 4 + rg][64] = accl[r][rg];
    }
  }
  __syncthreads();

  // 512 threads x 2 items: item -> (row = item>>4 in 0..63, 4 d). Sum 8.
#pragma unroll
  for (int ii = 0; ii < 2; ++ii) {
    int item = ii * 512 + t;
    int row = item >> 4, dd = (item & 15) * 4;
    float4v s = {0, 0, 0, 0};
    float l = 0.f;
#pragma unroll
    for (int w2 = 0; w2 < 8; ++w2) {
      float4v pv = *reinterpret_cast<const float4v*>(&part[w2][row][dd]);
      s += pv;
      l += part[w2][row][64];
    }
    float rl = 1.0f / l;
    float o[4];
#pragma unroll
    for (int rg = 0; rg < 4; ++rg) {
      float v = s[rg] * rl;
      o[rg] = v > 0.f ? v : EXP2(v * LOG2E) - 1.0f;
    }
    int n2 = i0 + row;
    if (outf) {
      size_t oo = (size_t)n2 * DIMC + h * 64 + dd;
      *reinterpret_cast<float4v*>(outf + oo) = {o[0], o[1], o[2], o[3]};
    } else {
      int cg = h * 64 + dd;          // global col (multiple of 4)
      size_t pidx = packidx(n2, cg); // A-fragment-packed for layer-2 GEMM
      short4v ohv, olv;
#pragma unroll
      for (int rg = 0; rg < 4; ++rg) {
        __hip_bfloat16 hb = __float2bfloat16(o[rg]);
        ohv[rg] = (short)bf16_bits(hb);
        olv[rg] = (short)bf16_bits(__float2bfloat16(o[rg] - __bfloat162float(hb)));
      }
      *reinterpret_cast<short4v*>(outhi + pidx) = ohv;
      *reinterpret_cast<short4v*>(outlo + pidx) = olv;
    }
  }
}

extern "C" void kernel_launch(void* const* d_in, const int* in_sizes, int n_in,
                              void* d_out, int out_size, void* d_ws, size_t ws_size,
                              hipStream_t stream)
{
  // inputs: t, x, adj, W1, a1, W2, a2  (fp32 except adj int32)
  const float* x   = (const float*)d_in[1];
  const int*   adj = (const int*)d_in[2];
  const float* W1  = (const float*)d_in[3];
  const float* a1  = (const float*)d_in[4];
  const float* W2  = (const float*)d_in[5];
  const float* a2  = (const float*)d_in[6];

  char* ws = (char*)d_ws;
  size_t off = 0;
  auto alloc = [&](size_t b) { size_t o = off; off = (off + b + 255) & ~255ULL; return o; };
  size_t o_bits = alloc((size_t)N_NODES * 64 * 8);          // 2 MB bitmask
  size_t o_w1h  = alloc((size_t)DIMC * DIMC * 2);           // packed weights
  size_t o_w1l  = alloc((size_t)DIMC * DIMC * 2);
  size_t o_w2h  = alloc((size_t)DIMC * DIMC * 2);
  size_t o_w2l  = alloc((size_t)DIMC * DIMC * 2);
  size_t o_xh   = alloc((size_t)N_NODES * DIMC * 2);        // packed A operand
  size_t o_xl   = alloc((size_t)N_NODES * DIMC * 2);
  size_t o_bp   = alloc((size_t)N_NODES * DIMC * 2);        // Bpack (2 MB)
  size_t o_x2h  = alloc((size_t)N_NODES * DIMC * 2);        // packed layer-2 A
  size_t o_x2l  = alloc((size_t)N_NODES * DIMC * 2);
  size_t o_f12  = alloc((size_t)4 * NHEADS * N_NODES * 4);  // f1a,f2a,f1b,f2b

  unsigned long long* bits = (unsigned long long*)(ws + o_bits);
  unsigned short* w1h = (unsigned short*)(ws + o_w1h);
  unsigned short* w1l = (unsigned short*)(ws + o_w1l);
  unsigned short* w2h = (unsigned short*)(ws + o_w2h);
  unsigned short* w2l = (unsigned short*)(ws + o_w2l);
  unsigned short* xh  = (unsigned short*)(ws + o_xh);
  unsigned short* xl  = (unsigned short*)(ws + o_xl);
  unsigned short* bpk = (unsigned short*)(ws + o_bp);
  unsigned short* x2h = (unsigned short*)(ws + o_x2h);
  unsigned short* x2l = (unsigned short*)(ws + o_x2l);
  float* f12 = (float*)(ws + o_f12);
  float* f1a = f12;
  float* f2a = f12 + NHEADS * N_NODES;
  float* f1b = f12 + 2 * NHEADS * N_NODES;
  float* f2b = f12 + 3 * NHEADS * N_NODES;

  prep_kernel<<<66176, 256, 0, stream>>>(adj, bits, x, xh, xl, W1, W2,
                                         w1h, w1l, w2h, w2l, f12);

  auto layer = [&](const unsigned short* xih, const unsigned short* xil,
                   const unsigned short* wth, const unsigned short* wtl,
                   const float* av, float* f1p, float* f2p, float* outf,
                   unsigned short* oh, unsigned short* ol) {
    gemm_kernel<<<dim3(128, 8), 256, 0, stream>>>(xih, xil, wth, wtl, av,
                                                  f1p, f2p, bpk);
    attn_kernel<<<dim3(64, 4), 512, 0, stream>>>(bpk, f1p, f2p, bits,
                                                 outf, oh, ol);
  };

  layer(xh,  xl,  w1h, w1l, a1, f1a, f2a, nullptr,       x2h, x2l);
  layer(x2h, x2l, w2h, w2l, a2, f1b, f2b, (float*)d_out, nullptr, nullptr);
}

// Round 16
// 188.462 us; speedup vs baseline: 1.0255x; 1.0240x over previous
//
#include <hip/hip_runtime.h>
#include <hip/hip_bf16.h>

#define N_NODES 4096
#define DIMC    256   // H*D, also K of both layer GEMMs
#define NHEADS  4
#define LOG2E   1.44269504f

typedef __attribute__((ext_vector_type(8))) short  short8;
typedef __attribute__((ext_vector_type(4))) short  short4v;
typedef __attribute__((ext_vector_type(4))) float  float4v;

union S8U { short8 v; unsigned int u[4]; };

#if __has_builtin(__builtin_amdgcn_exp2f)
#define EXP2(x) __builtin_amdgcn_exp2f(x)
#else
#define EXP2(x) exp2f(x)
#endif

__device__ inline unsigned short bf16_bits(__hip_bfloat16 b) {
  union { __hip_bfloat16 b; unsigned short u; } cv; cv.b = b; return cv.u;
}

// Fragment-packed layout (operand of mfma_f32_16x16x32_bf16):
//   element (row r, k) lives at u16 index
//   ((r>>4)*8 + (k>>5))*512 + (((k>>3)&3)*16 + (r&15))*8 + (k&7)
// so a wave (lane = quad*16+col) loads one 16-row x 32-k fragment as a
// single contiguous 1-KB dwordx4 stream at frag_base + lane*8.
__device__ inline size_t packidx(int r, int k) {
  return ((size_t)(r >> 4) * 8 + (k >> 5)) * 512
       + (((k >> 3) & 3) * 16 + (r & 15)) * 8 + (k & 7);
}

// ------------- fused preprocessing: one dispatch, 4 phases ---------------
//  blocks [0, 65536)          : adjacency -> bitmask
//  blocks [65536, 66048)      : x fp32 -> A-fragment-packed split bf16
//  blocks [66048, 66112)      : W1/W2 -> B-fragment-packed split bf16
//  blocks [66112, 66176)      : zero the f1/f2 accumulators (256 KB)
__global__ __launch_bounds__(256) void prep_kernel(
    const int* __restrict__ adj, unsigned long long* __restrict__ bits,
    const float* __restrict__ x,
    unsigned short* __restrict__ xh, unsigned short* __restrict__ xl,
    const float* __restrict__ W1, const float* __restrict__ W2,
    unsigned short* __restrict__ w1h, unsigned short* __restrict__ w1l,
    unsigned short* __restrict__ w2h, unsigned short* __restrict__ w2l,
    float* __restrict__ f12zero)
{
  int b = blockIdx.x, t = threadIdx.x;
  if (b < 65536) {                      // ---- pack_adj
    int wid  = b * 4 + (t >> 6);
    int lane = t & 63;
    int row  = wid >> 6;
    int w64  = wid & 63;
    int v = adj[(size_t)row * N_NODES + w64 * 64 + lane];
    unsigned long long m = __ballot(v > 0);
    if (lane == 0) bits[row * 64 + w64] = m;
  } else if (b < 66048) {               // ---- split_pack (x)
    int g = (b - 65536) * 256 + t;      // 131072 threads
    int n = g >> 5, kb = (g & 31) * 8;
    const float* ip = x + (size_t)n * DIMC + kb;
    float4v v0 = *reinterpret_cast<const float4v*>(ip);
    float4v v1 = *reinterpret_cast<const float4v*>(ip + 4);
    short8 oh, ol;
#pragma unroll
    for (int i = 0; i < 8; ++i) {
      float f = (i < 4) ? v0[i] : v1[i - 4];
      __hip_bfloat16 hb = __float2bfloat16(f);
      oh[i] = (short)bf16_bits(hb);
      ol[i] = (short)bf16_bits(__float2bfloat16(f - __bfloat162float(hb)));
    }
    size_t idx = packidx(n, kb);
    *reinterpret_cast<short8*>(xh + idx) = oh;
    *reinterpret_cast<short8*>(xl + idx) = ol;
  } else if (b < 66112) {               // ---- wpack (W1 / W2)
    int bid = b - 66048;
    const float* W = (bid >> 5) ? W2 : W1;
    unsigned short* hi = (bid >> 5) ? w2h : w1h;
    unsigned short* lo = (bid >> 5) ? w2l : w1l;
    int g = (bid & 31) * 256 + t;       // 8192 threads per layer
    int c = g >> 5, kb = (g & 31) * 8;
    int h = c >> 6, d = c & 63;
    const float* wp = W + (size_t)h * DIMC * 64 + (size_t)kb * 64 + d;
    short8 oh, ol;
#pragma unroll
    for (int i = 0; i < 8; ++i) {
      float f = wp[i * 64];
      __hip_bfloat16 hb = __float2bfloat16(f);
      oh[i] = (short)bf16_bits(hb);
      ol[i] = (short)bf16_bits(__float2bfloat16(f - __bfloat162float(hb)));
    }
    size_t idx = packidx(c, kb);
    *reinterpret_cast<short8*>(hi + idx) = oh;
    *reinterpret_cast<short8*>(lo + idx) = ol;
  } else {                              // ---- zero f1/f2 (256 KB)
    int z = b - 66112;                  // 0..63
    reinterpret_cast<float4v*>(f12zero)[(size_t)z * 256 + t] = {0, 0, 0, 0};
  }
}

// ------- h GEMM (fragment-packed split-bf16) + f-vec + Bpack epilogue ----
// All four operand streams are contiguous 1-KB wave-loads per K-step.
// Epilogue 1: f1/f2 partials (dot of acc with a-vec halves over this
//   block's 16-col slices) via 16-lane shfl reduce + atomicAdd (LOG2E-
//   scaled). Replaces the fvec kernel; hA never goes to memory.
// Epilogue 2: Bpack (V in MFMA B-fragment order for attn).
// grid (128,8), block 256. blockIdx.x == jt, head = blockIdx.y>>1.
__global__ __launch_bounds__(256) void gemm_kernel(
    const unsigned short* __restrict__ Ah, const unsigned short* __restrict__ Al,
    const unsigned short* __restrict__ Bh, const unsigned short* __restrict__ Bl,
    const float* __restrict__ avec,
    float* __restrict__ f1L, float* __restrict__ f2L,
    unsigned short* __restrict__ Bpack)
{
  __shared__ float tl[32][33];
  int t = threadIdx.x;
  int wv = t >> 6, lane = t & 63, quad = lane >> 4, col = lane & 15;
  int bc = blockIdx.y * 32;
  int rt = blockIdx.x * 2 + (wv >> 1);   // 16-row tile index
  int ct = blockIdx.y * 2 + (wv & 1);    // 16-col tile index
  int r0 = blockIdx.x * 32 + (wv >> 1) * 16;
  int c0 = bc + (wv & 1) * 16;
  float4v acc = {0, 0, 0, 0};
  const unsigned short* ahp = Ah + (size_t)rt * 4096 + lane * 8;
  const unsigned short* alp = Al + (size_t)rt * 4096 + lane * 8;
  const unsigned short* bhp = Bh + (size_t)ct * 4096 + lane * 8;
  const unsigned short* blp = Bl + (size_t)ct * 4096 + lane * 8;
#pragma unroll
  for (int ks = 0; ks < 8; ++ks) {
    short8 ah = *reinterpret_cast<const short8*>(ahp + ks * 512);
    short8 al = *reinterpret_cast<const short8*>(alp + ks * 512);
    short8 bh = *reinterpret_cast<const short8*>(bhp + ks * 512);
    short8 bl = *reinterpret_cast<const short8*>(blp + ks * 512);
    acc = __builtin_amdgcn_mfma_f32_16x16x32_bf16(ah, bh, acc, 0, 0, 0);
    acc = __builtin_amdgcn_mfma_f32_16x16x32_bf16(ah, bl, acc, 0, 0, 0);
    acc = __builtin_amdgcn_mfma_f32_16x16x32_bf16(al, bh, acc, 0, 0, 0);
  }

  // ---- f1/f2 partial reduction (this block's 16-col slice of head hh)
  int hh = blockIdx.y >> 1;
  int d0 = (c0 + col) & 63;
  float av1 = avec[hh * 128 + d0];
  float av2 = avec[hh * 128 + 64 + d0];
#pragma unroll
  for (int r = 0; r < 4; ++r) {
    float v1 = acc[r] * av1;
    float v2 = acc[r] * av2;
#pragma unroll
    for (int o = 8; o >= 1; o >>= 1) {
      v1 += __shfl_xor(v1, o);
      v2 += __shfl_xor(v2, o);
    }
    if ((lane & 15) == 0) {
      int n = r0 + quad * 4 + r;
      atomicAdd(f1L + hh * N_NODES + n, v1 * LOG2E);
      atomicAdd(f2L + hh * N_NODES + n, v2 * LOG2E);
    }
  }

  // ---- Bpack epilogue (via LDS transpose of the 32x32 tile)
  int lr = (wv >> 1) * 16 + quad * 4, lc = (wv & 1) * 16 + col;
#pragma unroll
  for (int r = 0; r < 4; ++r) tl[lr + r][lc] = acc[r];
  __syncthreads();
  int tr = t >> 3, tc = (t & 7) * 4;   // tr: local c, tc: local j (4-wide)
  short4v oh;
#pragma unroll
  for (int k = 0; k < 4; ++k)
    oh[k] = (short)bf16_bits(__float2bfloat16(tl[tc + k][tr]));
  int c = bc + tr;
  int h = c >> 6, d = c & 63, db = d >> 4, colp = d & 15;
  int quadp = tc >> 3, jj = tc & 7;    // jj in {0,4}
  size_t fragu = (((size_t)(h * 128 + blockIdx.x) * 4 + db) * 64
                  + quadp * 16 + colp) * 8 + jj;
  *reinterpret_cast<short4v*>(Bpack + fragu) = oh;
}

// ------ fused masked-softmax attention, fragment-packed streaming --------
// grid (128, 4) = (32-row i-tile, head). block 512 = 8 waves; wave wv sweeps
// the disjoint j-range [wv*512, (wv+1)*512) for the SAME 32 i-rows, keeping
// TWO A-fragments against each B-fragment (10 MFMA per 4-KB B-load).
// Prologue (replaces fvec's global max): masks for 32 rows x 64 tiles
// (16 KB) preloaded to LDS; per-head f2 max (16 KB column) reduced through
// LDS. Main loop barrier-free; all global traffic contiguous.
__global__ __launch_bounds__(512, 4) void attn_kernel(
    const unsigned short* __restrict__ Bpack,
    const float* __restrict__ f1L, const float* __restrict__ f2L,
    const unsigned long long* __restrict__ bits64, // [4096][64]
    float* __restrict__ outf, unsigned short* __restrict__ outhi,
    unsigned short* __restrict__ outlo)
{
  __shared__ __align__(16) float part[8][32][68];  // 69.6 KB (aliased below)
  unsigned long long* lds_bits =
      reinterpret_cast<unsigned long long*>(&part[0][0][0]); // 16 KB: [tile][row]
  float* red = reinterpret_cast<float*>(&part[2][0][0]);     // 2 KB @ 17408
  int t = threadIdx.x;
  int wv = t >> 6, lane = t & 63, quad = lane >> 4, col = lane & 15;
  int it = blockIdx.x, h = blockIdx.y;
  int i0 = it * 32;
  int irow0 = i0 + col;              // rows for A-fragment 0
  int irow1 = i0 + 16 + col;         // rows for A-fragment 1

  // ---- mask preload: 32 rows x 64 tiles, coalesced read, [tile][row] LDS
  {
    int rr = t >> 4, tt = (t & 15) * 4;
    const unsigned long long* gsrc = bits64 + (size_t)(i0 + rr) * 64 + tt;
    unsigned long long m0 = gsrc[0], m1 = gsrc[1], m2 = gsrc[2], m3 = gsrc[3];
    lds_bits[(tt + 0) * 32 + rr] = m0;
    lds_bits[(tt + 1) * 32 + rr] = m1;
    lds_bits[(tt + 2) * 32 + rr] = m2;
    lds_bits[(tt + 3) * 32 + rr] = m3;
  }

  // ---- per-head f2 max over all 4096 nodes (LDS tree)
  const float* f2h = f2L + h * N_NODES;
  {
    float4v ma = *reinterpret_cast<const float4v*>(f2h + t * 8);
    float4v mb = *reinterpret_cast<const float4v*>(f2h + t * 8 + 4);
    red[t] = fmaxf(fmaxf(fmaxf(ma[0], ma[1]), fmaxf(ma[2], ma[3])),
                   fmaxf(fmaxf(mb[0], mb[1]), fmaxf(mb[2], mb[3])));
  }
  __syncthreads();
#pragma unroll
  for (int s2 = 256; s2 >= 1; s2 >>= 1) {
    if (t < s2) red[t] = fmaxf(red[t], red[t + s2]);
    __syncthreads();
  }
  float f2m = red[0];

  float f1i0 = f1L[h * N_NODES + irow0];
  float f1i1 = f1L[h * N_NODES + irow1];
  float s00 = f1i0 + f2m;
  float m0 = fmaxf(s00, 0.2f * s00); // lrelu monotone -> valid upper-bound shift
  float f1m0 = f1i0 - m0;
  float cm0 = -0.8f * m0;
  float s01 = f1i1 + f2m;
  float m1 = fmaxf(s01, 0.2f * s01);
  float f1m1 = f1i1 - m1;
  float cm1 = -0.8f * m1;

  // wave's fragment stream: 16 steps x 4 db x 512 u16, contiguous
  const unsigned short* bp =
      Bpack + ((size_t)(h * 128 + wv * 16)) * 4 * 512 + lane * 8;
  int jbase = wv * 512;

  float4v acc0[4] = {{0,0,0,0},{0,0,0,0},{0,0,0,0},{0,0,0,0}};
  float4v acc1[4] = {{0,0,0,0},{0,0,0,0},{0,0,0,0},{0,0,0,0}};
  float4v accl0 = {0, 0, 0, 0}, accl1 = {0, 0, 0, 0};
  S8U ones;
  ones.u[0] = ones.u[1] = ones.u[2] = ones.u[3] = 0x3F803F80u; // bf16 1.0 x2

  for (int s = 0; s < 16; ++s) {     // 16 x 32-j steps, no barriers
    int j0 = jbase + s * 32;
    int tg = j0 >> 6;                // global mask tile = wv*8 + (s>>1)
    unsigned long long wq0 = lds_bits[tg * 32 + col];
    unsigned long long wq1 = lds_bits[tg * 32 + col + 16];
    int sh = (j0 & 32) | (quad * 8);
    unsigned wb0 = (unsigned)(wq0 >> sh);
    unsigned wb1 = (unsigned)(wq1 >> sh);
    const float* fp = f2h + j0 + quad * 8;
    float4v fa = *reinterpret_cast<const float4v*>(fp);
    float4v fb = *reinterpret_cast<const float4v*>(fp + 4);
    const unsigned short* bs = bp + (size_t)s * 2048;
    short8 b0 = *reinterpret_cast<const short8*>(bs);
    short8 b1 = *reinterpret_cast<const short8*>(bs + 512);
    short8 b2 = *reinterpret_cast<const short8*>(bs + 1024);
    short8 b3 = *reinterpret_cast<const short8*>(bs + 1536);
    float w0[8], w1[8];
#pragma unroll
    for (int jj = 0; jj < 8; ++jj) {
      float fv = (jj < 4) ? fa[jj] : fb[jj - 4];
      float sp0 = f1m0 + fv;
      float tb0 = __builtin_fmaf(0.2f, sp0, cm0);
      float e0 = EXP2(fmaxf(sp0, tb0));
      w0[jj] = (wb0 & (1u << jj)) ? e0 : 0.0f;
      float sp1 = f1m1 + fv;
      float tb1 = __builtin_fmaf(0.2f, sp1, cm1);
      float e1 = EXP2(fmaxf(sp1, tb1));
      w1[jj] = (wb1 & (1u << jj)) ? e1 : 0.0f;
    }
    S8U afr0, afr1;
#pragma unroll
    for (int k2 = 0; k2 < 4; ++k2) { // truncate-pack two fp32 -> bf16x2
      afr0.u[k2] = __builtin_amdgcn_perm(__float_as_uint(w0[2 * k2 + 1]),
                                         __float_as_uint(w0[2 * k2]),
                                         0x07060302u);
      afr1.u[k2] = __builtin_amdgcn_perm(__float_as_uint(w1[2 * k2 + 1]),
                                         __float_as_uint(w1[2 * k2]),
                                         0x07060302u);
    }
    acc0[0] = __builtin_amdgcn_mfma_f32_16x16x32_bf16(afr0.v, b0, acc0[0], 0, 0, 0);
    acc0[1] = __builtin_amdgcn_mfma_f32_16x16x32_bf16(afr0.v, b1, acc0[1], 0, 0, 0);
    acc0[2] = __builtin_amdgcn_mfma_f32_16x16x32_bf16(afr0.v, b2, acc0[2], 0, 0, 0);
    acc0[3] = __builtin_amdgcn_mfma_f32_16x16x32_bf16(afr0.v, b3, acc0[3], 0, 0, 0);
    accl0   = __builtin_amdgcn_mfma_f32_16x16x32_bf16(afr0.v, ones.v, accl0, 0, 0, 0);
    acc1[0] = __builtin_amdgcn_mfma_f32_16x16x32_bf16(afr1.v, b0, acc1[0], 0, 0, 0);
    acc1[1] = __builtin_amdgcn_mfma_f32_16x16x32_bf16(afr1.v, b1, acc1[1], 0, 0, 0);
    acc1[2] = __builtin_amdgcn_mfma_f32_16x16x32_bf16(afr1.v, b2, acc1[2], 0, 0, 0);
    acc1[3] = __builtin_amdgcn_mfma_f32_16x16x32_bf16(afr1.v, b3, acc1[3], 0, 0, 0);
    accl1   = __builtin_amdgcn_mfma_f32_16x16x32_bf16(afr1.v, ones.v, accl1, 0, 0, 0);
  }

  __syncthreads();   // all mask/red reads complete before aliased part writes

  // C/D layout: col=lane&15 (d sub-col), row=quad*4+reg (i). Park partials.
#pragma unroll
  for (int db = 0; db < 4; ++db)
#pragma unroll
    for (int r = 0; r < 4; ++r) {
      part[wv][quad * 4 + r][db * 16 + col] = acc0[db][r];
      part[wv][16 + quad * 4 + r][db * 16 + col] = acc1[db][r];
    }
  if (col == 0) {
#pragma unroll
    for (int r = 0; r < 4; ++r) {
      part[wv][quad * 4 + r][64] = accl0[r];
      part[wv][16 + quad * 4 + r][64] = accl1[r];
    }
  }
  __syncthreads();

  // 512 threads: t -> (row = t>>4 in 0..31, 4 d at (t&15)*4). Sum 8 partials.
  int row = t >> 4, dd = (t & 15) * 4;
  float4v s = {0, 0, 0, 0};
  float l = 0.f;
#pragma unroll
  for (int w2 = 0; w2 < 8; ++w2) {
    float4v pv = *reinterpret_cast<const float4v*>(&part[w2][row][dd]);
    s += pv;
    l += part[w2][row][64];
  }
  float rl = 1.0f / l;
  float o[4];
#pragma unroll
  for (int r = 0; r < 4; ++r) {
    float v = s[r] * rl;
    o[r] = v > 0.f ? v : EXP2(v * LOG2E) - 1.0f;
  }
  int n2 = i0 + row;
  if (outf) {
    size_t oo = (size_t)n2 * DIMC + h * 64 + dd;
    *reinterpret_cast<float4v*>(outf + oo) = {o[0], o[1], o[2], o[3]};
  } else {
    int cg = h * 64 + dd;            // global col (multiple of 4)
    size_t pidx = packidx(n2, cg);   // A-fragment-packed for layer-2 GEMM
    short4v ohv, olv;
#pragma unroll
    for (int r = 0; r < 4; ++r) {
      __hip_bfloat16 hb = __float2bfloat16(o[r]);
      ohv[r] = (short)bf16_bits(hb);
      olv[r] = (short)bf16_bits(__float2bfloat16(o[r] - __bfloat162float(hb)));
    }
    *reinterpret_cast<short4v*>(outhi + pidx) = ohv;
    *reinterpret_cast<short4v*>(outlo + pidx) = olv;
  }
}

extern "C" void kernel_launch(void* const* d_in, const int* in_sizes, int n_in,
                              void* d_out, int out_size, void* d_ws, size_t ws_size,
                              hipStream_t stream)
{
  // inputs: t, x, adj, W1, a1, W2, a2  (fp32 except adj int32)
  const float* x   = (const float*)d_in[1];
  const int*   adj = (const int*)d_in[2];
  const float* W1  = (const float*)d_in[3];
  const float* a1  = (const float*)d_in[4];
  const float* W2  = (const float*)d_in[5];
  const float* a2  = (const float*)d_in[6];

  char* ws = (char*)d_ws;
  size_t off = 0;
  auto alloc = [&](size_t b) { size_t o = off; off = (off + b + 255) & ~255ULL; return o; };
  size_t o_bits = alloc((size_t)N_NODES * 64 * 8);          // 2 MB bitmask
  size_t o_w1h  = alloc((size_t)DIMC * DIMC * 2);           // packed weights
  size_t o_w1l  = alloc((size_t)DIMC * DIMC * 2);
  size_t o_w2h  = alloc((size_t)DIMC * DIMC * 2);
  size_t o_w2l  = alloc((size_t)DIMC * DIMC * 2);
  size_t o_xh   = alloc((size_t)N_NODES * DIMC * 2);        // packed A operand
  size_t o_xl   = alloc((size_t)N_NODES * DIMC * 2);
  size_t o_bp   = alloc((size_t)N_NODES * DIMC * 2);        // Bpack (2 MB)
  size_t o_x2h  = alloc((size_t)N_NODES * DIMC * 2);        // packed layer-2 A
  size_t o_x2l  = alloc((size_t)N_NODES * DIMC * 2);
  size_t o_f12  = alloc((size_t)4 * NHEADS * N_NODES * 4);  // f1a,f2a,f1b,f2b

  unsigned long long* bits = (unsigned long long*)(ws + o_bits);
  unsigned short* w1h = (unsigned short*)(ws + o_w1h);
  unsigned short* w1l = (unsigned short*)(ws + o_w1l);
  unsigned short* w2h = (unsigned short*)(ws + o_w2h);
  unsigned short* w2l = (unsigned short*)(ws + o_w2l);
  unsigned short* xh  = (unsigned short*)(ws + o_xh);
  unsigned short* xl  = (unsigned short*)(ws + o_xl);
  unsigned short* bpk = (unsigned short*)(ws + o_bp);
  unsigned short* x2h = (unsigned short*)(ws + o_x2h);
  unsigned short* x2l = (unsigned short*)(ws + o_x2l);
  float* f12 = (float*)(ws + o_f12);
  float* f1a = f12;
  float* f2a = f12 + NHEADS * N_NODES;
  float* f1b = f12 + 2 * NHEADS * N_NODES;
  float* f2b = f12 + 3 * NHEADS * N_NODES;

  prep_kernel<<<66176, 256, 0, stream>>>(adj, bits, x, xh, xl, W1, W2,
                                         w1h, w1l, w2h, w2l, f12);

  auto layer = [&](const unsigned short* xih, const unsigned short* xil,
                   const unsigned short* wth, const unsigned short* wtl,
                   const float* av, float* f1p, float* f2p, float* outf,
                   unsigned short* oh, unsigned short* ol) {
    gemm_kernel<<<dim3(128, 8), 256, 0, stream>>>(xih, xil, wth, wtl, av,
                                                  f1p, f2p, bpk);
    attn_kernel<<<dim3(128, 4), 512, 0, stream>>>(bpk, f1p, f2p, bits,
                                                  outf, oh, ol);
  };

  layer(xh,  xl,  w1h, w1l, a1, f1a, f2a, nullptr,       x2h, x2l);
  layer(x2h, x2l, w2h, w2l, a2, f1b, f2b, (float*)d_out, nullptr, nullptr);
}